// Round 13
// baseline (25.099 us; speedup 1.0000x reference)
//
#include <hip/hip_runtime.h>
#include <stdint.h>

#define B_SZ    8
#define N_PTS   4096
#define C_IN    64
#define C_OUT   64
#define KNN     16
#define ROWS    (B_SZ * N_PTS)      // 32768

typedef __attribute__((ext_vector_type(8))) short v8s;   // 8 bf16 (4 VGPR)
typedef __attribute__((ext_vector_type(4))) float v4f;   // MFMA acc

__device__ inline unsigned short f2bf(float f) {         // RNE f32->bf16
    unsigned int u = __float_as_uint(f);
    return (unsigned short)((u + 0x7FFFu + ((u >> 16) & 1u)) >> 16);
}

// Pack 8 floats (2 float4) into a bf16 MFMA fragment.
__device__ inline v8s pack8(float4 q0, float4 q1) {
    v8s a;
    a[0] = (short)f2bf(q0.x); a[1] = (short)f2bf(q0.y);
    a[2] = (short)f2bf(q0.z); a[3] = (short)f2bf(q0.w);
    a[4] = (short)f2bf(q1.x); a[5] = (short)f2bf(q1.y);
    a[6] = (short)f2bf(q1.z); a[7] = (short)f2bf(q1.w);
    return a;
}

#define PITCH 68

// ---------------------------------------------------------------------------
// Kernel 1: nbuf projection (MFMA).  nbuf[r][o] = x[r]·W2[o]  (bf16)
// 32 rows/block, 4 waves = (row half) x (col half).
// x staged in LDS (coalesced); W2 frags built per-wave straight from w
// (w = 32 KB, L1/L2-hot after first touch; 8 contiguous floats per frag-reg
// = 2 dwordx4 per lane — no wprep kernel, no wfrag round-trip).
// B-frag element j at lane l: col = base+(l&15), k = ks*32+8*(l>>4)+j,
// B[k][col] = W2[col][k] = w[col*128 + 64 + k].
// ---------------------------------------------------------------------------
__global__ __launch_bounds__(256, 4) void proj_nbuf(
    const float* __restrict__ x,
    const float* __restrict__ w,
    unsigned short* __restrict__ nbuf)
{
    __shared__ float sm[32][PITCH];         // 8.5 KiB

    const int t    = threadIdx.x;
    const int lane = t & 63;
    const int wv   = t >> 6;
    const int b    = blockIdx.x & 7;        // batch == XCD affinity
    const int tn   = blockIdx.x >> 3;       // 0..127
    const int r0g  = b * N_PTS + tn * 32;

    // stage 32 x-rows (8 KB) coalesced
    {
        const float4* xsrc = (const float4*)(x + (size_t)r0g * C_IN);
#pragma unroll
        for (int i = 0; i < 2; ++i) {
            const int idx = i * 256 + t;
            *(float4*)&sm[idx >> 4][(idx & 15) * 4] = xsrc[idx];
        }
    }

    const int rq  = wv & 1;                 // rows rq*16..+15
    const int ch  = wv >> 1;                // cols ch*32..+31
    const int rl0 = rq * 16;

    // W2 fragments from global w (L1-hot)
    v8s bfrag[2][2];
#pragma unroll
    for (int ct = 0; ct < 2; ++ct) {
        const int col = ch * 32 + ct * 16 + (lane & 15);
#pragma unroll
        for (int ks = 0; ks < 2; ++ks) {
            const float* wp = w + col * 128 + 64 + ks * 32 + 8 * (lane >> 4);
            bfrag[ct][ks] = pack8(*(const float4*)wp, *(const float4*)(wp + 4));
        }
    }

    __syncthreads();

    const int rl   = rl0 + (lane & 15);
    const int koff = 8 * (lane >> 4);
    v8s afrag[2];
#pragma unroll
    for (int ks = 0; ks < 2; ++ks) {
        const float* xp = &sm[rl][ks * 32 + koff];
        afrag[ks] = pack8(*(const float4*)xp, *(const float4*)(xp + 4));
    }

    v4f acc[2];
#pragma unroll
    for (int ct = 0; ct < 2; ++ct)
        acc[ct] = (v4f){0.f, 0.f, 0.f, 0.f};
#pragma unroll
    for (int ks = 0; ks < 2; ++ks)
#pragma unroll
        for (int ct = 0; ct < 2; ++ct)
            acc[ct] = __builtin_amdgcn_mfma_f32_16x16x32_bf16(
                afrag[ks], bfrag[ct][ks], acc[ct], 0, 0, 0);

    const int orow = rl0 + (lane >> 4) * 4;
    const int ccol = lane & 15;
#pragma unroll
    for (int ct = 0; ct < 2; ++ct)
#pragma unroll
        for (int reg = 0; reg < 4; ++reg)
            nbuf[(size_t)(r0g + orow + reg) * C_OUT + ch * 32 + ct * 16 + ccol] =
                f2bf(acc[ct][reg]);
}

// ---------------------------------------------------------------------------
// Kernel 2: fused cbuf(MFMA, LDS-only) + gather + max + relu + store.
// eidx prefetched at kernel entry (hides HBM latency under staging + MFMA).
// cbuf-weight frags (W1-W2) built per-wave from global w.
//   out[b][o][n] = relu( cbuf[n][o] + max_k nbuf[idx[n,k]][o] )
// ---------------------------------------------------------------------------
__global__ __launch_bounds__(256, 4) void gather_fused(
    const float* __restrict__ x,
    const float* __restrict__ w,
    const float* __restrict__ bias,
    const int* __restrict__ eidx,
    const unsigned short* __restrict__ nbuf,
    float* __restrict__ out)
{
    __shared__ float sm[32][PITCH];         // 8.5 KiB, reused x->cbuf->result

    const int t    = threadIdx.x;
    const int lane = t & 63;
    const int wv   = t >> 6;
    const int b    = blockIdx.x & 7;        // batch == XCD
    const int tn   = blockIdx.x >> 3;       // 0..127
    const int n0   = tn * 32;
    const int r0g  = b * N_PTS + n0;

    // ---- prefetch eidx for Phase C (issue first, consume last) ----
    int pidx[2];
#pragma unroll
    for (int i = 0; i < 2; ++i)
        pidx[i] = eidx[(size_t)(r0g + wv * 8 + i * 4) * KNN + lane];

    // ---- Phase A: stage 32 x-rows (8 KB) coalesced ----
    {
        const float4* xsrc = (const float4*)(x + (size_t)r0g * C_IN);
#pragma unroll
        for (int i = 0; i < 2; ++i) {
            const int idx = i * 256 + t;
            *(float4*)&sm[idx >> 4][(idx & 15) * 4] = xsrc[idx];
        }
    }

    // ---- Phase B: cbuf tile via MFMA ----
    const int rq  = wv & 1;
    const int ch  = wv >> 1;
    const int rl0 = rq * 16;

    // (W1 - W2) fragments from global w (L1-hot)
    v8s bfrag[2][2];
#pragma unroll
    for (int ct = 0; ct < 2; ++ct) {
        const int col = ch * 32 + ct * 16 + (lane & 15);
#pragma unroll
        for (int ks = 0; ks < 2; ++ks) {
            const float* wp = w + col * 128 + ks * 32 + 8 * (lane >> 4);
            const float4 a0 = *(const float4*)wp;
            const float4 a1 = *(const float4*)(wp + 4);
            const float4 b0 = *(const float4*)(wp + 64);
            const float4 b1 = *(const float4*)(wp + 68);
            bfrag[ct][ks] = pack8(
                make_float4(a0.x - b0.x, a0.y - b0.y, a0.z - b0.z, a0.w - b0.w),
                make_float4(a1.x - b1.x, a1.y - b1.y, a1.z - b1.z, a1.w - b1.w));
        }
    }

    __syncthreads();

    const int rl   = rl0 + (lane & 15);
    const int koff = 8 * (lane >> 4);
    v8s afrag[2];
#pragma unroll
    for (int ks = 0; ks < 2; ++ks) {
        const float* xp = &sm[rl][ks * 32 + koff];
        afrag[ks] = pack8(*(const float4*)xp, *(const float4*)(xp + 4));
    }

    v4f acc[2];
#pragma unroll
    for (int ct = 0; ct < 2; ++ct) {
        const float bv = bias[ch * 32 + ct * 16 + (lane & 15)];
        acc[ct] = (v4f){bv, bv, bv, bv};
    }
#pragma unroll
    for (int ks = 0; ks < 2; ++ks)
#pragma unroll
        for (int ct = 0; ct < 2; ++ct)
            acc[ct] = __builtin_amdgcn_mfma_f32_16x16x32_bf16(
                afrag[ks], bfrag[ct][ks], acc[ct], 0, 0, 0);

    __syncthreads();                        // all afrag reads done

    const int orow = rl0 + (lane >> 4) * 4;
    const int ccol = lane & 15;
#pragma unroll
    for (int ct = 0; ct < 2; ++ct)
#pragma unroll
        for (int reg = 0; reg < 4; ++reg)
            sm[orow + reg][ch * 32 + ct * 16 + ccol] = acc[ct][reg];

    __syncthreads();

    // ---- Phase C: gather + max + relu ----
    const unsigned short* nb = nbuf + (size_t)b * N_PTS * C_OUT;
    const int o4  = (lane & 15) * 4;
    const int sub = lane >> 4;

#pragma unroll
    for (int i = 0; i < 2; ++i) {
        const int rbl   = wv * 8 + i * 4;   // local row base
        const int myidx = pidx[i] & (N_PTS - 1);

        const float4 cv = *(const float4*)&sm[rbl + sub][o4];

        float m0 = -1e30f, m1 = -1e30f, m2 = -1e30f, m3 = -1e30f;
#pragma unroll
        for (int k = 0; k < KNN; ++k) {
            const int idx = __shfl(myidx, (lane & 48) | k);
            const uint2 v = *(const uint2*)(nb + (size_t)idx * C_OUT + o4);
            m0 = fmaxf(m0, __uint_as_float(v.x << 16));
            m1 = fmaxf(m1, __uint_as_float(v.x & 0xffff0000u));
            m2 = fmaxf(m2, __uint_as_float(v.y << 16));
            m3 = fmaxf(m3, __uint_as_float(v.y & 0xffff0000u));
        }

        const int nl = rbl + sub;
        sm[nl][o4 + 0] = fmaxf(cv.x + m0, 0.f);   // relu(max)==max(relu)
        sm[nl][o4 + 1] = fmaxf(cv.y + m1, 0.f);
        sm[nl][o4 + 2] = fmaxf(cv.z + m2, 0.f);
        sm[nl][o4 + 3] = fmaxf(cv.w + m3, 0.f);
    }

    __syncthreads();

    // ---- transposed coalesced store ----
    float* ob = out + (size_t)b * C_OUT * N_PTS + n0;
    const int nn = lane & 31;
    const int oh = lane >> 5;
#pragma unroll
    for (int j = 0; j < 8; ++j) {
        const int o = wv * 16 + j * 2 + oh;
        ob[(size_t)o * N_PTS + nn] = sm[nn][o];   // 2x128B segments
    }
}

// ---------------------------------------------------------------------------
extern "C" void kernel_launch(void* const* d_in, const int* in_sizes, int n_in,
                              void* d_out, int out_size, void* d_ws, size_t ws_size,
                              hipStream_t stream)
{
    const float* x    = (const float*)d_in[0];
    const int*   eidx = (const int*)d_in[1];    // int64 in ref -> int32 here
    const float* w    = (const float*)d_in[2];  // (64, 128)
    const float* bias = (const float*)d_in[3];  // (64,)
    float*       out  = (float*)d_out;          // (8, 64, 64, 64) f32

    unsigned short* nbuf = (unsigned short*)d_ws;   // 4 MiB

    proj_nbuf<<<ROWS / 32, 256, 0, stream>>>(x, w, nbuf);
    gather_fused<<<ROWS / 32, 256, 0, stream>>>(x, w, bias, eidx, nbuf, out);
}

// Round 14
// 20.546 us; speedup vs baseline: 1.2216x; 1.2216x over previous
//
#include <hip/hip_runtime.h>
#include <stdint.h>

#define B_SZ    8
#define N_PTS   4096
#define C_IN    64
#define C_OUT   64
#define KNN     16
#define ROWS    (B_SZ * N_PTS)      // 32768

typedef __attribute__((ext_vector_type(8))) short v8s;   // 8 bf16 (4 VGPR)
typedef __attribute__((ext_vector_type(4))) float v4f;   // MFMA acc

__device__ inline unsigned short f2bf(float f) {         // RNE f32->bf16
    unsigned int u = __float_as_uint(f);
    return (unsigned short)((u + 0x7FFFu + ((u >> 16) & 1u)) >> 16);
}

__device__ inline v8s pack8(float4 q0, float4 q1) {
    v8s a;
    a[0] = (short)f2bf(q0.x); a[1] = (short)f2bf(q0.y);
    a[2] = (short)f2bf(q0.z); a[3] = (short)f2bf(q0.w);
    a[4] = (short)f2bf(q1.x); a[5] = (short)f2bf(q1.y);
    a[6] = (short)f2bf(q1.z); a[7] = (short)f2bf(q1.w);
    return a;
}

#define PITCH 68

// ---------------------------------------------------------------------------
// Kernel 0: pack combined weights B[k][col] (64x128) into MFMA B-fragment
// order (LDS-staged, coalesced; ~1us).  frag tid = ct*128 + ks*64 + lane:
// cols ct*16+(lane&15), k = ks*32 + 8*(lane>>4) + j.
//   col <  64: B[k][col] = W1[col][k] - W2[col][k]   (cbuf weights)
//   col >= 64: B[k][col] = W2[col-64][k]             (nbuf weights)
// Amortized prep beats per-block recompute: building frags from w in the
// consumer waves costs 512B-stride scattered loads (round-13: +4.3us).
// ---------------------------------------------------------------------------
__global__ __launch_bounds__(256) void wprep_kernel(const float* __restrict__ w,
                                                    v8s* __restrict__ wfrag)
{
    __shared__ float wl[2 * C_IN * C_OUT];   // 32 KiB
    const int t = threadIdx.x;
    {
        const float4* src = (const float4*)w;
        float4*       dst = (float4*)wl;
#pragma unroll
        for (int i = 0; i < 8; ++i)
            dst[i * 256 + t] = src[i * 256 + t];
    }
    __syncthreads();

    const int tid  = blockIdx.x * 256 + t;   // 0..1023 (grid = 4)
    const int lane = tid & 63;
    const int ks   = (tid >> 6) & 1;
    const int ct   = tid >> 7;
    const int col  = ct * 16 + (lane & 15);
    const int kb   = ks * 32 + 8 * (lane >> 4);

    v8s f;
#pragma unroll
    for (int j = 0; j < 8; ++j) {
        const int k = kb + j;
        const float v = (col < 64)
            ? (wl[col * 128 + k] - wl[col * 128 + 64 + k])
            : wl[(col - 64) * 128 + 64 + k];
        f[j] = (short)f2bf(v);
    }
    wfrag[tid] = f;
}

// ---------------------------------------------------------------------------
// Kernel 1: nbuf-only projection (MFMA).  nbuf[r][o] = x[r]·W2[o]  (bf16)
// 64 rows/block, 4 waves; wave wv: rows wv*16..+15, all 64 cols.
// bfrag = W2 frags (wfrag ct 4..7, coalesced 16B/lane, L2-hot).
// ---------------------------------------------------------------------------
__global__ __launch_bounds__(256, 2) void proj_nbuf(
    const float* __restrict__ x,
    const v8s*  __restrict__ wfrag,
    unsigned short* __restrict__ nbuf)
{
    const int lane  = threadIdx.x & 63;
    const int wv    = threadIdx.x >> 6;
    const int batch = blockIdx.x & 7;                    // XCD-affine
    const int chunk = blockIdx.x >> 3;                   // 0..63
    const int r0    = batch * N_PTS + chunk * 64 + wv * 16;

    v8s bfrag[4][2];
#pragma unroll
    for (int ct = 0; ct < 4; ++ct)
#pragma unroll
        for (int ks = 0; ks < 2; ++ks)
            bfrag[ct][ks] = wfrag[((4 + ct) * 2 + ks) * 64 + lane];

    const int arow = r0 + (lane & 15);
    const int koff = 8 * (lane >> 4);
    v8s afrag[2];
#pragma unroll
    for (int ks = 0; ks < 2; ++ks) {
        const float* xp = x + (size_t)arow * C_IN + ks * 32 + koff;
        afrag[ks] = pack8(*(const float4*)xp, *(const float4*)(xp + 4));
    }

    v4f acc[4];
#pragma unroll
    for (int ct = 0; ct < 4; ++ct)
        acc[ct] = (v4f){0.f, 0.f, 0.f, 0.f};

#pragma unroll
    for (int ks = 0; ks < 2; ++ks)
#pragma unroll
        for (int ct = 0; ct < 4; ++ct)
            acc[ct] = __builtin_amdgcn_mfma_f32_16x16x32_bf16(
                afrag[ks], bfrag[ct][ks], acc[ct], 0, 0, 0);

    const int crow0 = r0 + (lane >> 4) * 4;
    const int ccol  = lane & 15;
#pragma unroll
    for (int ct = 0; ct < 4; ++ct)
#pragma unroll
        for (int reg = 0; reg < 4; ++reg)
            nbuf[(size_t)(crow0 + reg) * C_OUT + ct * 16 + ccol] =
                f2bf(acc[ct][reg]);
}

// ---------------------------------------------------------------------------
// Kernel 2: fused cbuf(MFMA, LDS-only) + gather + max + relu + store.
// eidx prefetched at kernel entry; wfrag loads issued BEFORE the staging
// barrier (both overlap Phase A's HBM latency).
//   out[b][o][n] = relu( cbuf[n][o] + max_k nbuf[idx[n,k]][o] )
// ---------------------------------------------------------------------------
__global__ __launch_bounds__(256, 4) void gather_fused(
    const float* __restrict__ x,
    const v8s*  __restrict__ wfrag,
    const float* __restrict__ bias,
    const int* __restrict__ eidx,
    const unsigned short* __restrict__ nbuf,
    float* __restrict__ out)
{
    __shared__ float sm[32][PITCH];         // 8.5 KiB, reused x->cbuf->result

    const int t    = threadIdx.x;
    const int lane = t & 63;
    const int wv   = t >> 6;                // wave 0..3
    const int b    = blockIdx.x & 7;        // batch == XCD
    const int tn   = blockIdx.x >> 3;       // 0..127
    const int n0   = tn * 32;
    const int r0g  = b * N_PTS + n0;

    // ---- prefetch eidx for Phase C (issue first, consume last) ----
    int pidx[2];
#pragma unroll
    for (int i = 0; i < 2; ++i)
        pidx[i] = eidx[(size_t)(r0g + wv * 8 + i * 4) * KNN + lane];

    // ---- B-frags (W1-W2 half of wfrag): global L2 loads, pre-barrier ----
    const int rq  = wv & 1;                 // rows rq*16..+15
    const int ch  = wv >> 1;                // cols ch*32..+31
    v8s bfrag[2][2];
#pragma unroll
    for (int ct = 0; ct < 2; ++ct)
#pragma unroll
        for (int ks = 0; ks < 2; ++ks)
            bfrag[ct][ks] = wfrag[((ch * 2 + ct) * 2 + ks) * 64 + lane];

    // ---- Phase A: stage 32 x-rows (8 KB) coalesced ----
    {
        const float4* xsrc = (const float4*)(x + (size_t)r0g * C_IN);
#pragma unroll
        for (int i = 0; i < 2; ++i) {
            const int idx = i * 256 + t;    // 0..511
            *(float4*)&sm[idx >> 4][(idx & 15) * 4] = xsrc[idx];
        }
    }
    __syncthreads();

    // ---- Phase B: cbuf tile via MFMA ----
    const int rl0  = rq * 16;
    const int rl   = rl0 + (lane & 15);
    const int koff = 8 * (lane >> 4);
    v8s afrag[2];
#pragma unroll
    for (int ks = 0; ks < 2; ++ks) {
        const float* xp = &sm[rl][ks * 32 + koff];
        afrag[ks] = pack8(*(const float4*)xp, *(const float4*)(xp + 4));
    }

    v4f acc[2];
#pragma unroll
    for (int ct = 0; ct < 2; ++ct) {
        const float bv = bias[ch * 32 + ct * 16 + (lane & 15)];
        acc[ct] = (v4f){bv, bv, bv, bv};
    }
#pragma unroll
    for (int ks = 0; ks < 2; ++ks)
#pragma unroll
        for (int ct = 0; ct < 2; ++ct)
            acc[ct] = __builtin_amdgcn_mfma_f32_16x16x32_bf16(
                afrag[ks], bfrag[ct][ks], acc[ct], 0, 0, 0);

    __syncthreads();                        // all afrag reads done

    const int orow = rl0 + (lane >> 4) * 4;
    const int ccol = lane & 15;
#pragma unroll
    for (int ct = 0; ct < 2; ++ct)
#pragma unroll
        for (int reg = 0; reg < 4; ++reg)
            sm[orow + reg][ch * 32 + ct * 16 + ccol] = acc[ct][reg];

    __syncthreads();

    // ---- Phase C: gather + max + relu ----
    const unsigned short* nb = nbuf + (size_t)b * N_PTS * C_OUT;
    const int o4  = (lane & 15) * 4;
    const int sub = lane >> 4;

#pragma unroll
    for (int i = 0; i < 2; ++i) {
        const int rbl   = wv * 8 + i * 4;   // local row base
        const int myidx = pidx[i] & (N_PTS - 1);

        const float4 cv = *(const float4*)&sm[rbl + sub][o4];

        float m0 = -1e30f, m1 = -1e30f, m2 = -1e30f, m3 = -1e30f;
#pragma unroll
        for (int k = 0; k < KNN; ++k) {
            const int idx = __shfl(myidx, (lane & 48) | k);
            const uint2 v = *(const uint2*)(nb + (size_t)idx * C_OUT + o4);
            m0 = fmaxf(m0, __uint_as_float(v.x << 16));
            m1 = fmaxf(m1, __uint_as_float(v.x & 0xffff0000u));
            m2 = fmaxf(m2, __uint_as_float(v.y << 16));
            m3 = fmaxf(m3, __uint_as_float(v.y & 0xffff0000u));
        }

        const int nl = rbl + sub;
        sm[nl][o4 + 0] = fmaxf(cv.x + m0, 0.f);   // relu(max)==max(relu)
        sm[nl][o4 + 1] = fmaxf(cv.y + m1, 0.f);
        sm[nl][o4 + 2] = fmaxf(cv.z + m2, 0.f);
        sm[nl][o4 + 3] = fmaxf(cv.w + m3, 0.f);
    }

    __syncthreads();

    // ---- transposed coalesced store ----
    float* ob = out + (size_t)b * C_OUT * N_PTS + n0;
    const int nn = lane & 31;
    const int oh = lane >> 5;
#pragma unroll
    for (int j = 0; j < 8; ++j) {
        const int o = wv * 16 + j * 2 + oh;
        ob[(size_t)o * N_PTS + nn] = sm[nn][o];   // 2x128B segments
    }
}

// ---------------------------------------------------------------------------
extern "C" void kernel_launch(void* const* d_in, const int* in_sizes, int n_in,
                              void* d_out, int out_size, void* d_ws, size_t ws_size,
                              hipStream_t stream)
{
    const float* x    = (const float*)d_in[0];
    const int*   eidx = (const int*)d_in[1];    // int64 in ref -> int32 here
    const float* w    = (const float*)d_in[2];  // (64, 128)
    const float* bias = (const float*)d_in[3];  // (64,)
    float*       out  = (float*)d_out;          // (8, 64, 64, 64) f32

    unsigned short* nbuf  = (unsigned short*)d_ws;                 // 4 MiB
    v8s*            wfrag = (v8s*)((char*)d_ws + (size_t)ROWS * C_OUT * 2);

    wprep_kernel<<<4, 256, 0, stream>>>(w, wfrag);
    proj_nbuf<<<ROWS / 64, 256, 0, stream>>>(x, wfrag, nbuf);
    gather_fused<<<ROWS / 32, 256, 0, stream>>>(x, wfrag, bias, eidx, nbuf, out);
}